// Round 18
// baseline (1397.930 us; speedup 1.0000x reference)
//
#include <hip/hip_runtime.h>
#include <math.h>

constexpr int B_   = 64;
constexpr int T_   = 512;
constexpr int D_   = 512;
constexpr int H_   = 1024;
constexpr int IMG_ = 2048;
constexpr int NWG  = 256;
constexpr int NTHR = 256;

constexpr size_t SLOT_U16   = (size_t)B_ * H_;                 // 65536 u16 = 128 KiB
constexpr size_t RING_BYTES = (size_t)(T_ + 1) * SLOT_U16 * 2; // ~67.2 MB
constexpr size_t XBF_BYTES  = (size_t)B_ * T_ * D_ * 2;        // 33.5 MB
constexpr unsigned SENT32   = 0x7F7F7F7Fu;   // memset 0x7F: bf16 pair ~3.4e38, unreachable by h*d

typedef __attribute__((ext_vector_type(8))) short    short8;
typedef __attribute__((ext_vector_type(4))) float    f32x4;
typedef __attribute__((ext_vector_type(4))) unsigned uint4v;

__device__ __forceinline__ unsigned short f2bf(float f) {
  unsigned u = __float_as_uint(f);
  u += 0x7FFFu + ((u >> 16) & 1u);     // RTNE
  return (unsigned short)(u >> 16);
}
__device__ __forceinline__ float sigf(float v) {
  return __fdividef(1.0f, 1.0f + __expf(-v));
}
__device__ __forceinline__ float tanhfast(float v) {
  v = fminf(15.0f, fmaxf(-15.0f, v));
  const float e = __expf(2.0f * v);
  return __fdividef(e - 1.0f, e + 1.0f);
}
// pack 8 f32 (two float4) -> short8 bf16 via v_cvt_pk_bf16_f32 (RTNE)
__device__ __forceinline__ short8 pk8(const float4 a, const float4 b) {
  union { unsigned u[4]; short8 s; } r;
  asm("v_cvt_pk_bf16_f32 %0, %1, %2" : "=v"(r.u[0]) : "v"(a.x), "v"(a.y));
  asm("v_cvt_pk_bf16_f32 %0, %1, %2" : "=v"(r.u[1]) : "v"(a.z), "v"(a.w));
  asm("v_cvt_pk_bf16_f32 %0, %1, %2" : "=v"(r.u[2]) : "v"(b.x), "v"(b.y));
  asm("v_cvt_pk_bf16_f32 %0, %1, %2" : "=v"(r.u[3]) : "v"(b.z), "v"(b.w));
  return r.s;
}

// One-time x repack: [B,T,D] f32 -> quarter fragment-major bf16.
// u16 off = ((t*4 + b/16)*16 + k/32)*512 + ((k/8)&3)*128 + (b&15)*8 + (k&7)
__global__ void __launch_bounds__(NTHR)
x_repack_kernel(const float* __restrict__ x, unsigned short* __restrict__ x_bf) {
  const int idx = blockIdx.x * NTHR + threadIdx.x;   // 2^21 chunks of 8
  const int k8 = idx & 63;
  const int t  = (idx >> 6) & 511;
  const int b  = idx >> 15;
  const float* px = x + ((size_t)b * T_ + t) * D_ + k8 * 8;
  const float4 v0 = *(const float4*)px;
  const float4 v1 = *(const float4*)(px + 4);
  const size_t off = ((size_t)(t * 4 + (b >> 4)) * 16 + (k8 >> 2)) * 512
                   + (size_t)(k8 & 3) * 128 + (size_t)(b & 15) * 8;
  *(short8*)(x_bf + off) = pk8(v0, v1);
}

// Persistent multimodal-LSTM v14 = v13 (canary sync, dbuf gaccs, 1282us) +
//  (1) x-MFMAs issued BETWEEN h-load issue and vmcnt(0) -> initial L3 latency
//      hidden under 16 MFMAs;
//  (2) process-as-ready: chunks that cleared sentinel are MFMA'd immediately,
//      stragglers re-polled after -- tail skew overlaps with compute;
//  (3) hfr register copies eliminated (MFMA direct from tmp).
// Coherence protocol unchanged (validated R16/R17): publish = relaxed agent
// u32 write-through; consume = sc0sc1 bypass dwordx4; staleness on payload.
// RING=0 fallback keeps the R9 flag protocol verbatim.
template<int RING, int XBF>
__global__ void __launch_bounds__(NTHR, 1)
mmlstm_persistent(const float* __restrict__ x,
                  const unsigned short* __restrict__ x_bf,
                  const float* __restrict__ img,
                  const float* __restrict__ W_ih,
                  const float* __restrict__ W_hh,
                  const float* __restrict__ b_ih,
                  const float* __restrict__ b_hh,
                  const float* __restrict__ W_m,
                  float* __restrict__ out,
                  float* __restrict__ hn,
                  float* __restrict__ cn,
                  unsigned* __restrict__ flags,
                  unsigned short* __restrict__ ring)
{
  __shared__ float gaccs[2][4][16][68]; // double-buffered cross-wave partials
  __shared__ float bias_lds[64];
  __shared__ char  ldspad[52 * 1024];   // total LDS > 80KB -> 1 WG/CU placement

  const int tid  = threadIdx.x;
  const int lane = tid & 63;
  const int wv   = tid >> 6;
  const int wg   = blockIdx.x;
  const int q    = wg & 3;              // quarter
  const int cgid = wg >> 2;             // 0..63 within quarter
  const int b0   = q * 16;
  const int j0   = cgid * 16;

  ((volatile char*)ldspad)[tid] = 0;

  unsigned* myflags = flags + q * 64;
  unsigned* myslot  = myflags + cgid;

  // ---- one-time: W fragments into registers ----
  const int cloc = lane & 15;
  const int ko8  = (lane >> 4) << 3;
  short8 wx[4][4], wh[4][8];
  #pragma unroll
  for (int tile = 0; tile < 4; ++tile) {
    const int grow = tile * H_ + j0 + cloc;
    #pragma unroll
    for (int sx = 0; sx < 4; ++sx) {
      const float* p = W_ih + (size_t)grow * D_ + (wv + 4 * sx) * 32 + ko8;
      wx[tile][sx] = pk8(*(const float4*)p, *(const float4*)(p + 4));
    }
    #pragma unroll
    for (int sh = 0; sh < 8; ++sh) {
      const float* p = W_hh + (size_t)grow * H_ + (wv + 4 * sh) * 32 + ko8;
      wh[tile][sh] = pk8(*(const float4*)p, *(const float4*)(p + 4));
    }
  }
  if (tid < 64) {
    const int grow = (tid >> 4) * H_ + j0 + (tid & 15);
    bias_lds[tid] = b_ih[grow] + b_hh[grow];
  }

  // ---- per-thread ownership: thread = (b_l, jj), 1 h value ----
  const int b_l = tid >> 4;
  const int jj  = tid & 15;
  const int b   = b0 + b_l;
  const int j   = j0 + jj;

  // publish offset (u16, within quarter-slot) for (b_l, j)
  const int poff = (j >> 5) * 512 + ((j >> 3) & 3) * 128 + b_l * 8 + (j & 7);

  // multimodal gate d[b][j] = img[b] . W_m[j]
  float dval = 0.0f;
  {
    const float4* ir = (const float4*)(img + (size_t)b * IMG_);
    const float4* wr = (const float4*)(W_m + (size_t)j * IMG_);
    for (int k = 0; k < IMG_ / 4; ++k) {
      const float4 a = ir[k];
      const float4 w = wr[k];
      dval += a.x * w.x + a.y * w.y + a.z * w.z + a.w * w.w;
    }
  }

  // publish h0*d = 0 into slot 0 (coalesced u32 write-through)
  if ((jj & 1) == 0)
    __hip_atomic_store((unsigned*)(ring + (size_t)q * 16384 + poff), 0u,
                       __ATOMIC_RELAXED, __HIP_MEMORY_SCOPE_AGENT);

  float cstate = 0.0f;

  __syncthreads();                      // publishes drained; bias/W ready
  if (RING == 0 && tid == 0)
    __hip_atomic_store(myslot, 1u, __ATOMIC_RELAXED, __HIP_MEMORY_SCOPE_AGENT);

  auto pollFlags = [&](unsigned target) {   // RING=0 path (R9 protocol)
    for (;;) {
      const unsigned f = __hip_atomic_load(myflags + lane, __ATOMIC_RELAXED,
                                           __HIP_MEMORY_SCOPE_AGENT);
      if (__all(f >= target)) break;
    }
  };

  short8 xr[4];
  auto xprefetch = [&](int t) {
    if (XBF) {
      const unsigned short* xb = x_bf + ((size_t)t * 4 + q) * 8192;
      #pragma unroll
      for (int sx = 0; sx < 4; ++sx)
        xr[sx] = *(const short8*)(xb + (size_t)(wv + 4 * sx) * 512 + lane * 8);
    } else {
      const float* rb = x + ((size_t)(b0 + cloc) * T_ + t) * D_ + ko8;
      #pragma unroll
      for (int sx = 0; sx < 4; ++sx) {
        const float* p = rb + (wv + 4 * sx) * 32;
        xr[sx] = pk8(*(const float4*)p, *(const float4*)(p + 4));
      }
    }
  };

  xprefetch(0);

  for (int t = 0; t < T_; ++t) {
    const unsigned short* sp = ring + (size_t)(RING ? t : (t & 1)) * SLOT_U16
                             + (size_t)q * 16384;
    f32x4 ac[4];

    if (RING) {
      // ---- issue 8 h-chunk canary loads ----
      uint4v tmp[8];
      #pragma unroll
      for (int sh = 0; sh < 8; ++sh) {
        const unsigned short* ap = sp + (size_t)(wv + 4 * sh) * 512 + lane * 8;
        asm volatile("global_load_dwordx4 %0, %1, off sc0 sc1"
                     : "=&v"(tmp[sh]) : "v"(ap));
      }
      // ---- x-part MFMAs overlap the load latency ----
      #pragma unroll
      for (int tile = 0; tile < 4; ++tile) ac[tile] = (f32x4){0.f, 0.f, 0.f, 0.f};
      #pragma unroll
      for (int sx = 0; sx < 4; ++sx) {
        #pragma unroll
        for (int tile = 0; tile < 4; ++tile)
          ac[tile] = __builtin_amdgcn_mfma_f32_16x16x32_bf16(xr[sx], wx[tile][sx], ac[tile], 0, 0, 0);
      }
      asm volatile("s_waitcnt vmcnt(0)" ::: "memory");
      __builtin_amdgcn_sched_barrier(0);
      // ---- process-as-ready; collect stragglers ----
      unsigned pend = 0;
      #pragma unroll
      for (int sh = 0; sh < 8; ++sh) {
        bool ok = true;
        #pragma unroll
        for (int e = 0; e < 4; ++e) ok &= (tmp[sh][e] != SENT32);
        if (__all(ok)) {
          const short8 hf = *(short8*)&tmp[sh];
          #pragma unroll
          for (int tile = 0; tile < 4; ++tile)
            ac[tile] = __builtin_amdgcn_mfma_f32_16x16x32_bf16(hf, wh[tile][sh], ac[tile], 0, 0, 0);
        } else pend |= (1u << sh);
      }
      while (pend) {                    // re-poll only stale chunks
        #pragma unroll
        for (int sh = 0; sh < 8; ++sh) {
          if (pend & (1u << sh)) {
            const unsigned short* ap = sp + (size_t)(wv + 4 * sh) * 512 + lane * 8;
            asm volatile("global_load_dwordx4 %0, %1, off sc0 sc1"
                         : "=&v"(tmp[sh]) : "v"(ap));
          }
        }
        asm volatile("s_waitcnt vmcnt(0)" ::: "memory");
        __builtin_amdgcn_sched_barrier(0);
        #pragma unroll
        for (int sh = 0; sh < 8; ++sh) {
          if (pend & (1u << sh)) {
            bool ok = true;
            #pragma unroll
            for (int e = 0; e < 4; ++e) ok &= (tmp[sh][e] != SENT32);
            if (__all(ok)) {
              const short8 hf = *(short8*)&tmp[sh];
              #pragma unroll
              for (int tile = 0; tile < 4; ++tile)
                ac[tile] = __builtin_amdgcn_mfma_f32_16x16x32_bf16(hf, wh[tile][sh], ac[tile], 0, 0, 0);
              pend &= ~(1u << sh);
            }
          }
        }
      }
    } else {
      pollFlags((unsigned)(t + 1));
      asm volatile("" ::: "memory");
      uint4v tmp[8];
      #pragma unroll
      for (int sh = 0; sh < 8; ++sh) {
        const unsigned short* ap = sp + (size_t)(wv + 4 * sh) * 512 + lane * 8;
        asm volatile("global_load_dwordx4 %0, %1, off sc0 sc1" : "=&v"(tmp[sh]) : "v"(ap));
      }
      asm volatile("s_waitcnt vmcnt(0)" ::: "memory");
      __builtin_amdgcn_sched_barrier(0);
      #pragma unroll
      for (int tile = 0; tile < 4; ++tile) ac[tile] = (f32x4){0.f, 0.f, 0.f, 0.f};
      #pragma unroll
      for (int sx = 0; sx < 4; ++sx) {
        #pragma unroll
        for (int tile = 0; tile < 4; ++tile)
          ac[tile] = __builtin_amdgcn_mfma_f32_16x16x32_bf16(xr[sx], wx[tile][sx], ac[tile], 0, 0, 0);
      }
      #pragma unroll
      for (int sh = 0; sh < 8; ++sh) {
        const short8 hf = *(short8*)&tmp[sh];
        #pragma unroll
        for (int tile = 0; tile < 4; ++tile)
          ac[tile] = __builtin_amdgcn_mfma_f32_16x16x32_bf16(hf, wh[tile][sh], ac[tile], 0, 0, 0);
      }
    }

    // ---- cross-wave reduce into buffer (t&1); C/D: col=lane&15, row=(lane>>4)*4+rr ----
    {
      const int crow = (lane >> 4) * 4;
      #pragma unroll
      for (int tile = 0; tile < 4; ++tile) {
        #pragma unroll
        for (int rr = 0; rr < 4; ++rr)
          gaccs[t & 1][wv][crow + rr][tile * 16 + cloc] = ac[tile][rr];
      }
    }
    asm volatile("s_waitcnt lgkmcnt(0)" ::: "memory");
    __builtin_amdgcn_s_barrier();
    __builtin_amdgcn_sched_barrier(0);

    // ---- cell update: thread owns (b, j) ----
    float gv[4];
    #pragma unroll
    for (int g = 0; g < 4; ++g) {
      const int c = g * 16 + jj;
      gv[g] = gaccs[t & 1][0][b_l][c] + gaccs[t & 1][1][b_l][c]
            + gaccs[t & 1][2][b_l][c] + gaccs[t & 1][3][b_l][c]
            + bias_lds[c];
    }
    const float ig = sigf(gv[0]);
    const float fg = sigf(gv[1]);
    const float gg = tanhfast(gv[2]);
    const float og = sigf(gv[3]);
    cstate = fg * cstate + ig * gg;
    const float h = og * tanhfast(cstate);

    // ---- publish h*d to slot t+1 (1 coalesced u32 per even thread) ----
    {
      const unsigned hd  = f2bf(h * dval);
      const unsigned nxt = __shfl_down((int)hd, 1);
      if ((jj & 1) == 0)
        __hip_atomic_store((unsigned*)(ring + (size_t)(RING ? (t + 1) : ((t + 1) & 1)) * SLOT_U16
                                       + (size_t)q * 16384 + poff),
                           hd | (nxt << 16),
                           __ATOMIC_RELAXED, __HIP_MEMORY_SCOPE_AGENT);
    }

    if (RING == 0) {
      __syncthreads();                  // vmcnt(0)+barrier: publishes drained
      if (t < T_ - 1 && tid == 0)
        __hip_atomic_store(myslot, (unsigned)(t + 2), __ATOMIC_RELAXED, __HIP_MEMORY_SCOPE_AGENT);
    }
    // RING=1: no epilogue barrier -- gaccs double-buffered, canary handles sync

    // off the release path:
    __builtin_nontemporal_store(h, &out[((size_t)b * T_ + t) * H_ + j]);
    if (t == T_ - 1) {
      hn[(size_t)b * H_ + j] = h;
      cn[(size_t)b * H_ + j] = cstate;
    } else {
      xprefetch(t + 1);                 // overlaps next poll
    }
  }
}

extern "C" void kernel_launch(void* const* d_in, const int* in_sizes, int n_in,
                              void* d_out, int out_size, void* d_ws, size_t ws_size,
                              hipStream_t stream) {
  (void)in_sizes; (void)n_in; (void)out_size;
  const float* x    = (const float*)d_in[0];
  const float* img  = (const float*)d_in[1];
  const float* W_ih = (const float*)d_in[2];
  const float* W_hh = (const float*)d_in[3];
  const float* b_ih = (const float*)d_in[4];
  const float* b_hh = (const float*)d_in[5];
  const float* W_m  = (const float*)d_in[6];

  float* out = (float*)d_out;
  float* hn  = out + (size_t)B_ * T_ * H_;
  float* cn  = hn + (size_t)B_ * H_;

  unsigned*       flags = (unsigned*)d_ws;
  unsigned short* ring  = (unsigned short*)((char*)d_ws + 4096);
  unsigned short* x_bf  = (unsigned short*)((char*)d_ws + 4096 + RING_BYTES);

  hipMemsetAsync(d_ws, 0, 4096, stream);   // flag array (fallback paths)

  if (ws_size >= 4096 + RING_BYTES + XBF_BYTES) {
    hipMemsetAsync(ring, 0x7F, RING_BYTES, stream);   // canary sentinel fill
    hipLaunchKernelGGL(x_repack_kernel, dim3((B_ * T_ * D_ / 8) / NTHR), dim3(NTHR), 0, stream,
                       x, x_bf);
    hipLaunchKernelGGL((mmlstm_persistent<1, 1>), dim3(NWG), dim3(NTHR), 0, stream,
                       x, x_bf, img, W_ih, W_hh, b_ih, b_hh, W_m, out, hn, cn, flags, ring);
  } else if (ws_size >= 4096 + RING_BYTES) {
    hipMemsetAsync(ring, 0x7F, RING_BYTES, stream);
    hipLaunchKernelGGL((mmlstm_persistent<1, 0>), dim3(NWG), dim3(NTHR), 0, stream,
                       x, x_bf, img, W_ih, W_hh, b_ih, b_hh, W_m, out, hn, cn, flags, ring);
  } else {
    hipLaunchKernelGGL((mmlstm_persistent<0, 0>), dim3(NWG), dim3(NTHR), 0, stream,
                       x, x_bf, img, W_ih, W_hh, b_ih, b_hh, W_m, out, hn, cn, flags, ring);
  }
}

// Round 19
// 1281.516 us; speedup vs baseline: 1.0908x; 1.0908x over previous
//
#include <hip/hip_runtime.h>
#include <math.h>

constexpr int B_   = 64;
constexpr int T_   = 512;
constexpr int D_   = 512;
constexpr int H_   = 1024;
constexpr int IMG_ = 2048;
constexpr int NWG  = 256;
constexpr int NTHR = 256;

constexpr size_t SLOT_U16   = (size_t)B_ * H_;                 // 65536 u16 = 128 KiB
constexpr size_t RING_BYTES = (size_t)(T_ + 1) * SLOT_U16 * 2; // ~67.2 MB
constexpr size_t XBF_BYTES  = (size_t)B_ * T_ * D_ * 2;        // 33.5 MB
constexpr unsigned SENT32   = 0x7F7F7F7Fu;   // memset 0x7F: bf16 pair ~3.4e38, unreachable by h*d

typedef __attribute__((ext_vector_type(8))) short    short8;
typedef __attribute__((ext_vector_type(4))) float    f32x4;
typedef __attribute__((ext_vector_type(4))) unsigned uint4v;

__device__ __forceinline__ unsigned short f2bf(float f) {
  unsigned u = __float_as_uint(f);
  u += 0x7FFFu + ((u >> 16) & 1u);     // RTNE
  return (unsigned short)(u >> 16);
}
__device__ __forceinline__ float sigf(float v) {
  return __fdividef(1.0f, 1.0f + __expf(-v));
}
__device__ __forceinline__ float tanhfast(float v) {
  v = fminf(15.0f, fmaxf(-15.0f, v));
  const float e = __expf(2.0f * v);
  return __fdividef(e - 1.0f, e + 1.0f);
}
// pack 8 f32 (two float4) -> short8 bf16 via v_cvt_pk_bf16_f32 (RTNE)
__device__ __forceinline__ short8 pk8(const float4 a, const float4 b) {
  union { unsigned u[4]; short8 s; } r;
  asm("v_cvt_pk_bf16_f32 %0, %1, %2" : "=v"(r.u[0]) : "v"(a.x), "v"(a.y));
  asm("v_cvt_pk_bf16_f32 %0, %1, %2" : "=v"(r.u[1]) : "v"(a.z), "v"(a.w));
  asm("v_cvt_pk_bf16_f32 %0, %1, %2" : "=v"(r.u[2]) : "v"(b.x), "v"(b.y));
  asm("v_cvt_pk_bf16_f32 %0, %1, %2" : "=v"(r.u[3]) : "v"(b.z), "v"(b.w));
  return r.s;
}

// One-time x repack: [B,T,D] f32 -> quarter fragment-major bf16.
// u16 off = ((t*4 + b/16)*16 + k/32)*512 + ((k/8)&3)*128 + (b&15)*8 + (k&7)
__global__ void __launch_bounds__(NTHR)
x_repack_kernel(const float* __restrict__ x, unsigned short* __restrict__ x_bf) {
  const int idx = blockIdx.x * NTHR + threadIdx.x;   // 2^21 chunks of 8
  const int k8 = idx & 63;
  const int t  = (idx >> 6) & 511;
  const int b  = idx >> 15;
  const float* px = x + ((size_t)b * T_ + t) * D_ + k8 * 8;
  const float4 v0 = *(const float4*)px;
  const float4 v1 = *(const float4*)(px + 4);
  const size_t off = ((size_t)(t * 4 + (b >> 4)) * 16 + (k8 >> 2)) * 512
                   + (size_t)(k8 & 3) * 128 + (size_t)(b & 15) * 8;
  *(short8*)(x_bf + off) = pk8(v0, v1);
}

// Persistent multimodal-LSTM v15 = v13 verbatim (best: 1282us @ R17).
// Canary sync: ring memset to 0x7F; consumers poll own fragment chunks via
// coalesced sc0sc1 dwordx4 until all u32 != sentinel; selective re-poll of
// stale chunks only; double-buffered gaccs (parity t&1) -> single s_barrier
// per step. Publish = relaxed agent u32 write-through (coherent point).
// v14's process-as-ready/x-MFMA-overlap REVERTED (regressed to 1398us:
// per-chunk branch+check overhead exceeded the latency it hid).
// RING=0 fallback keeps the R9 flag protocol verbatim.
template<int RING, int XBF>
__global__ void __launch_bounds__(NTHR, 1)
mmlstm_persistent(const float* __restrict__ x,
                  const unsigned short* __restrict__ x_bf,
                  const float* __restrict__ img,
                  const float* __restrict__ W_ih,
                  const float* __restrict__ W_hh,
                  const float* __restrict__ b_ih,
                  const float* __restrict__ b_hh,
                  const float* __restrict__ W_m,
                  float* __restrict__ out,
                  float* __restrict__ hn,
                  float* __restrict__ cn,
                  unsigned* __restrict__ flags,
                  unsigned short* __restrict__ ring)
{
  __shared__ float gaccs[2][4][16][68]; // double-buffered cross-wave partials
  __shared__ float bias_lds[64];
  __shared__ char  ldspad[52 * 1024];   // total LDS > 80KB -> 1 WG/CU placement

  const int tid  = threadIdx.x;
  const int lane = tid & 63;
  const int wv   = tid >> 6;
  const int wg   = blockIdx.x;
  const int q    = wg & 3;              // quarter
  const int cgid = wg >> 2;             // 0..63 within quarter
  const int b0   = q * 16;
  const int j0   = cgid * 16;

  ((volatile char*)ldspad)[tid] = 0;

  unsigned* myflags = flags + q * 64;
  unsigned* myslot  = myflags + cgid;

  // ---- one-time: W fragments into registers ----
  const int cloc = lane & 15;
  const int ko8  = (lane >> 4) << 3;
  short8 wx[4][4], wh[4][8];
  #pragma unroll
  for (int tile = 0; tile < 4; ++tile) {
    const int grow = tile * H_ + j0 + cloc;
    #pragma unroll
    for (int sx = 0; sx < 4; ++sx) {
      const float* p = W_ih + (size_t)grow * D_ + (wv + 4 * sx) * 32 + ko8;
      wx[tile][sx] = pk8(*(const float4*)p, *(const float4*)(p + 4));
    }
    #pragma unroll
    for (int sh = 0; sh < 8; ++sh) {
      const float* p = W_hh + (size_t)grow * H_ + (wv + 4 * sh) * 32 + ko8;
      wh[tile][sh] = pk8(*(const float4*)p, *(const float4*)(p + 4));
    }
  }
  if (tid < 64) {
    const int grow = (tid >> 4) * H_ + j0 + (tid & 15);
    bias_lds[tid] = b_ih[grow] + b_hh[grow];
  }

  // ---- per-thread ownership: thread = (b_l, jj), 1 h value ----
  const int b_l = tid >> 4;
  const int jj  = tid & 15;
  const int b   = b0 + b_l;
  const int j   = j0 + jj;

  // publish offset (u16, within quarter-slot) for (b_l, j)
  const int poff = (j >> 5) * 512 + ((j >> 3) & 3) * 128 + b_l * 8 + (j & 7);

  // multimodal gate d[b][j] = img[b] . W_m[j]
  float dval = 0.0f;
  {
    const float4* ir = (const float4*)(img + (size_t)b * IMG_);
    const float4* wr = (const float4*)(W_m + (size_t)j * IMG_);
    for (int k = 0; k < IMG_ / 4; ++k) {
      const float4 a = ir[k];
      const float4 w = wr[k];
      dval += a.x * w.x + a.y * w.y + a.z * w.z + a.w * w.w;
    }
  }

  // publish h0*d = 0 into slot 0 (coalesced u32 write-through)
  if ((jj & 1) == 0)
    __hip_atomic_store((unsigned*)(ring + (size_t)q * 16384 + poff), 0u,
                       __ATOMIC_RELAXED, __HIP_MEMORY_SCOPE_AGENT);

  float cstate = 0.0f;

  __syncthreads();                      // publishes drained; bias/W ready
  if (RING == 0 && tid == 0)
    __hip_atomic_store(myslot, 1u, __ATOMIC_RELAXED, __HIP_MEMORY_SCOPE_AGENT);

  auto pollFlags = [&](unsigned target) {   // RING=0 path (R9 protocol)
    for (;;) {
      const unsigned f = __hip_atomic_load(myflags + lane, __ATOMIC_RELAXED,
                                           __HIP_MEMORY_SCOPE_AGENT);
      if (__all(f >= target)) break;
    }
  };

  short8 xr[4];
  auto xprefetch = [&](int t) {
    if (XBF) {
      const unsigned short* xb = x_bf + ((size_t)t * 4 + q) * 8192;
      #pragma unroll
      for (int sx = 0; sx < 4; ++sx)
        xr[sx] = *(const short8*)(xb + (size_t)(wv + 4 * sx) * 512 + lane * 8);
    } else {
      const float* rb = x + ((size_t)(b0 + cloc) * T_ + t) * D_ + ko8;
      #pragma unroll
      for (int sx = 0; sx < 4; ++sx) {
        const float* p = rb + (wv + 4 * sx) * 32;
        xr[sx] = pk8(*(const float4*)p, *(const float4*)(p + 4));
      }
    }
  };

  xprefetch(0);

  for (int t = 0; t < T_; ++t) {
    const unsigned short* sp = ring + (size_t)(RING ? t : (t & 1)) * SLOT_U16
                             + (size_t)q * 16384;
    short8 hfr[8];
    if (RING) {
      // ---- data-canary poll with selective re-load ----
      uint4v tmp[8];
      #pragma unroll
      for (int sh = 0; sh < 8; ++sh) {
        const unsigned short* ap = sp + (size_t)(wv + 4 * sh) * 512 + lane * 8;
        asm volatile("global_load_dwordx4 %0, %1, off sc0 sc1"
                     : "=&v"(tmp[sh]) : "v"(ap));
      }
      asm volatile("s_waitcnt vmcnt(0)" ::: "memory");
      __builtin_amdgcn_sched_barrier(0);
      unsigned pend = 0;
      #pragma unroll
      for (int sh = 0; sh < 8; ++sh) {
        bool ok = true;
        #pragma unroll
        for (int e = 0; e < 4; ++e) ok &= (tmp[sh][e] != SENT32);
        if (!__all(ok)) pend |= (1u << sh);
      }
      while (pend) {                    // re-load only stale chunks
        #pragma unroll
        for (int sh = 0; sh < 8; ++sh) {
          if (pend & (1u << sh)) {
            const unsigned short* ap = sp + (size_t)(wv + 4 * sh) * 512 + lane * 8;
            asm volatile("global_load_dwordx4 %0, %1, off sc0 sc1"
                         : "=&v"(tmp[sh]) : "v"(ap));
          }
        }
        asm volatile("s_waitcnt vmcnt(0)" ::: "memory");
        __builtin_amdgcn_sched_barrier(0);
        #pragma unroll
        for (int sh = 0; sh < 8; ++sh) {
          if (pend & (1u << sh)) {
            bool ok = true;
            #pragma unroll
            for (int e = 0; e < 4; ++e) ok &= (tmp[sh][e] != SENT32);
            if (__all(ok)) pend &= ~(1u << sh);
          }
        }
      }
      #pragma unroll
      for (int sh = 0; sh < 8; ++sh) hfr[sh] = *(short8*)&tmp[sh];
    } else {
      pollFlags((unsigned)(t + 1));
      asm volatile("" ::: "memory");
      uint4v tmp[8];
      #pragma unroll
      for (int sh = 0; sh < 8; ++sh) {
        const unsigned short* ap = sp + (size_t)(wv + 4 * sh) * 512 + lane * 8;
        asm volatile("global_load_dwordx4 %0, %1, off sc0 sc1" : "=&v"(tmp[sh]) : "v"(ap));
      }
      asm volatile("s_waitcnt vmcnt(0)" ::: "memory");
      __builtin_amdgcn_sched_barrier(0);
      #pragma unroll
      for (int sh = 0; sh < 8; ++sh)
        hfr[sh] = *(short8*)&tmp[sh];
    }

    // ---- MFMAs: 4 independent acc chains (one per gate tile) ----
    f32x4 ac[4];
    #pragma unroll
    for (int tile = 0; tile < 4; ++tile) ac[tile] = (f32x4){0.f, 0.f, 0.f, 0.f};
    #pragma unroll
    for (int sx = 0; sx < 4; ++sx) {
      #pragma unroll
      for (int tile = 0; tile < 4; ++tile)
        ac[tile] = __builtin_amdgcn_mfma_f32_16x16x32_bf16(xr[sx], wx[tile][sx], ac[tile], 0, 0, 0);
    }
    #pragma unroll
    for (int sh = 0; sh < 8; ++sh) {
      #pragma unroll
      for (int tile = 0; tile < 4; ++tile)
        ac[tile] = __builtin_amdgcn_mfma_f32_16x16x32_bf16(hfr[sh], wh[tile][sh], ac[tile], 0, 0, 0);
    }

    // ---- cross-wave reduce into buffer (t&1); C/D: col=lane&15, row=(lane>>4)*4+rr ----
    {
      const int crow = (lane >> 4) * 4;
      #pragma unroll
      for (int tile = 0; tile < 4; ++tile) {
        #pragma unroll
        for (int rr = 0; rr < 4; ++rr)
          gaccs[t & 1][wv][crow + rr][tile * 16 + cloc] = ac[tile][rr];
      }
    }
    asm volatile("s_waitcnt lgkmcnt(0)" ::: "memory");
    __builtin_amdgcn_s_barrier();
    __builtin_amdgcn_sched_barrier(0);

    // ---- cell update: thread owns (b, j) ----
    float gv[4];
    #pragma unroll
    for (int g = 0; g < 4; ++g) {
      const int c = g * 16 + jj;
      gv[g] = gaccs[t & 1][0][b_l][c] + gaccs[t & 1][1][b_l][c]
            + gaccs[t & 1][2][b_l][c] + gaccs[t & 1][3][b_l][c]
            + bias_lds[c];
    }
    const float ig = sigf(gv[0]);
    const float fg = sigf(gv[1]);
    const float gg = tanhfast(gv[2]);
    const float og = sigf(gv[3]);
    cstate = fg * cstate + ig * gg;
    const float h = og * tanhfast(cstate);

    // ---- publish h*d to slot t+1 (1 coalesced u32 per even thread) ----
    {
      const unsigned hd  = f2bf(h * dval);
      const unsigned nxt = __shfl_down((int)hd, 1);
      if ((jj & 1) == 0)
        __hip_atomic_store((unsigned*)(ring + (size_t)(RING ? (t + 1) : ((t + 1) & 1)) * SLOT_U16
                                       + (size_t)q * 16384 + poff),
                           hd | (nxt << 16),
                           __ATOMIC_RELAXED, __HIP_MEMORY_SCOPE_AGENT);
    }

    if (RING == 0) {
      __syncthreads();                  // vmcnt(0)+barrier: publishes drained
      if (t < T_ - 1 && tid == 0)
        __hip_atomic_store(myslot, (unsigned)(t + 2), __ATOMIC_RELAXED, __HIP_MEMORY_SCOPE_AGENT);
    }
    // RING=1: no epilogue barrier -- gaccs double-buffered, canary handles sync

    // off the release path:
    __builtin_nontemporal_store(h, &out[((size_t)b * T_ + t) * H_ + j]);
    if (t == T_ - 1) {
      hn[(size_t)b * H_ + j] = h;
      cn[(size_t)b * H_ + j] = cstate;
    } else {
      xprefetch(t + 1);                 // overlaps next poll
    }
  }
}

extern "C" void kernel_launch(void* const* d_in, const int* in_sizes, int n_in,
                              void* d_out, int out_size, void* d_ws, size_t ws_size,
                              hipStream_t stream) {
  (void)in_sizes; (void)n_in; (void)out_size;
  const float* x    = (const float*)d_in[0];
  const float* img  = (const float*)d_in[1];
  const float* W_ih = (const float*)d_in[2];
  const float* W_hh = (const float*)d_in[3];
  const float* b_ih = (const float*)d_in[4];
  const float* b_hh = (const float*)d_in[5];
  const float* W_m  = (const float*)d_in[6];

  float* out = (float*)d_out;
  float* hn  = out + (size_t)B_ * T_ * H_;
  float* cn  = hn + (size_t)B_ * H_;

  unsigned*       flags = (unsigned*)d_ws;
  unsigned short* ring  = (unsigned short*)((char*)d_ws + 4096);
  unsigned short* x_bf  = (unsigned short*)((char*)d_ws + 4096 + RING_BYTES);

  hipMemsetAsync(d_ws, 0, 4096, stream);   // flag array (fallback paths)

  if (ws_size >= 4096 + RING_BYTES + XBF_BYTES) {
    hipMemsetAsync(ring, 0x7F, RING_BYTES, stream);   // canary sentinel fill
    hipLaunchKernelGGL(x_repack_kernel, dim3((B_ * T_ * D_ / 8) / NTHR), dim3(NTHR), 0, stream,
                       x, x_bf);
    hipLaunchKernelGGL((mmlstm_persistent<1, 1>), dim3(NWG), dim3(NTHR), 0, stream,
                       x, x_bf, img, W_ih, W_hh, b_ih, b_hh, W_m, out, hn, cn, flags, ring);
  } else if (ws_size >= 4096 + RING_BYTES) {
    hipMemsetAsync(ring, 0x7F, RING_BYTES, stream);
    hipLaunchKernelGGL((mmlstm_persistent<1, 0>), dim3(NWG), dim3(NTHR), 0, stream,
                       x, x_bf, img, W_ih, W_hh, b_ih, b_hh, W_m, out, hn, cn, flags, ring);
  } else {
    hipLaunchKernelGGL((mmlstm_persistent<0, 0>), dim3(NWG), dim3(NTHR), 0, stream,
                       x, x_bf, img, W_ih, W_hh, b_ih, b_hh, W_m, out, hn, cn, flags, ring);
  }
}

// Round 21
// 1281.196 us; speedup vs baseline: 1.0911x; 1.0003x over previous
//
#include <hip/hip_runtime.h>
#include <math.h>

constexpr int B_   = 64;
constexpr int T_   = 512;
constexpr int D_   = 512;
constexpr int H_   = 1024;
constexpr int IMG_ = 2048;
constexpr int NWG  = 256;
constexpr int NTHR = 256;

constexpr size_t SLOT_U16   = (size_t)B_ * H_;                 // 65536 u16 = 128 KiB
constexpr size_t RING_BYTES = (size_t)(T_ + 1) * SLOT_U16 * 2; // ~67.2 MB
constexpr size_t XBF_BYTES  = (size_t)B_ * T_ * D_ * 2;        // 33.5 MB
constexpr unsigned SENT32   = 0x7F7F7F7Fu;   // memset 0x7F: bf16 pair ~3.4e38, unreachable by h*d

typedef __attribute__((ext_vector_type(8))) short    short8;
typedef __attribute__((ext_vector_type(4))) float    f32x4;
typedef __attribute__((ext_vector_type(4))) unsigned uint4v;

__device__ __forceinline__ unsigned short f2bf(float f) {
  unsigned u = __float_as_uint(f);
  u += 0x7FFFu + ((u >> 16) & 1u);     // RTNE
  return (unsigned short)(u >> 16);
}
__device__ __forceinline__ float sigf(float v) {
  return __fdividef(1.0f, 1.0f + __expf(-v));
}
__device__ __forceinline__ float tanhfast(float v) {
  v = fminf(15.0f, fmaxf(-15.0f, v));
  const float e = __expf(2.0f * v);
  return __fdividef(e - 1.0f, e + 1.0f);
}
// pack 8 f32 (two float4) -> short8 bf16 via v_cvt_pk_bf16_f32 (RTNE)
__device__ __forceinline__ short8 pk8(const float4 a, const float4 b) {
  union { unsigned u[4]; short8 s; } r;
  asm("v_cvt_pk_bf16_f32 %0, %1, %2" : "=v"(r.u[0]) : "v"(a.x), "v"(a.y));
  asm("v_cvt_pk_bf16_f32 %0, %1, %2" : "=v"(r.u[1]) : "v"(a.z), "v"(a.w));
  asm("v_cvt_pk_bf16_f32 %0, %1, %2" : "=v"(r.u[2]) : "v"(b.x), "v"(b.y));
  asm("v_cvt_pk_bf16_f32 %0, %1, %2" : "=v"(r.u[3]) : "v"(b.z), "v"(b.w));
  return r.s;
}

// One-time x repack: [B,T,D] f32 -> quarter fragment-major bf16.
// u16 off = ((t*4 + b/16)*16 + k/32)*512 + ((k/8)&3)*128 + (b&15)*8 + (k&7)
__global__ void __launch_bounds__(NTHR)
x_repack_kernel(const float* __restrict__ x, unsigned short* __restrict__ x_bf) {
  const int idx = blockIdx.x * NTHR + threadIdx.x;   // 2^21 chunks of 8
  const int k8 = idx & 63;
  const int t  = (idx >> 6) & 511;
  const int b  = idx >> 15;
  const float* px = x + ((size_t)b * T_ + t) * D_ + k8 * 8;
  const float4 v0 = *(const float4*)px;
  const float4 v1 = *(const float4*)(px + 4);
  const size_t off = ((size_t)(t * 4 + (b >> 4)) * 16 + (k8 >> 2)) * 512
                   + (size_t)(k8 & 3) * 128 + (size_t)(b & 15) * 8;
  *(short8*)(x_bf + off) = pk8(v0, v1);
}

// Persistent multimodal-LSTM v13 (validated best: 1282us @ R17, 1281us @ R19).
// Canary sync: ring memset to 0x7F; consumers poll own fragment chunks via
// coalesced sc0sc1 dwordx4 until all u32 != sentinel; selective re-poll of
// stale chunks only; double-buffered gaccs (parity t&1) -> single s_barrier
// per step. Publish = relaxed agent u32 write-through (coherent point).
// NOTE session history: v14 process-as-ready REGRESSED (1398us); v16 XCD-local
// sc0-only DEADLOCKED (XCC_ID roster unverifiable in-container + stale-L2
// sentinel spin). Both lines closed. RING=0 fallback keeps R9 flag protocol.
template<int RING, int XBF>
__global__ void __launch_bounds__(NTHR, 1)
mmlstm_persistent(const float* __restrict__ x,
                  const unsigned short* __restrict__ x_bf,
                  const float* __restrict__ img,
                  const float* __restrict__ W_ih,
                  const float* __restrict__ W_hh,
                  const float* __restrict__ b_ih,
                  const float* __restrict__ b_hh,
                  const float* __restrict__ W_m,
                  float* __restrict__ out,
                  float* __restrict__ hn,
                  float* __restrict__ cn,
                  unsigned* __restrict__ flags,
                  unsigned short* __restrict__ ring)
{
  __shared__ float gaccs[2][4][16][68]; // double-buffered cross-wave partials
  __shared__ float bias_lds[64];
  __shared__ char  ldspad[52 * 1024];   // total LDS > 80KB -> 1 WG/CU placement

  const int tid  = threadIdx.x;
  const int lane = tid & 63;
  const int wv   = tid >> 6;
  const int wg   = blockIdx.x;
  const int q    = wg & 3;              // quarter
  const int cgid = wg >> 2;             // 0..63 within quarter
  const int b0   = q * 16;
  const int j0   = cgid * 16;

  ((volatile char*)ldspad)[tid] = 0;

  unsigned* myflags = flags + q * 64;
  unsigned* myslot  = myflags + cgid;

  // ---- one-time: W fragments into registers ----
  const int cloc = lane & 15;
  const int ko8  = (lane >> 4) << 3;
  short8 wx[4][4], wh[4][8];
  #pragma unroll
  for (int tile = 0; tile < 4; ++tile) {
    const int grow = tile * H_ + j0 + cloc;
    #pragma unroll
    for (int sx = 0; sx < 4; ++sx) {
      const float* p = W_ih + (size_t)grow * D_ + (wv + 4 * sx) * 32 + ko8;
      wx[tile][sx] = pk8(*(const float4*)p, *(const float4*)(p + 4));
    }
    #pragma unroll
    for (int sh = 0; sh < 8; ++sh) {
      const float* p = W_hh + (size_t)grow * H_ + (wv + 4 * sh) * 32 + ko8;
      wh[tile][sh] = pk8(*(const float4*)p, *(const float4*)(p + 4));
    }
  }
  if (tid < 64) {
    const int grow = (tid >> 4) * H_ + j0 + (tid & 15);
    bias_lds[tid] = b_ih[grow] + b_hh[grow];
  }

  // ---- per-thread ownership: thread = (b_l, jj), 1 h value ----
  const int b_l = tid >> 4;
  const int jj  = tid & 15;
  const int b   = b0 + b_l;
  const int j   = j0 + jj;

  // publish offset (u16, within quarter-slot) for (b_l, j)
  const int poff = (j >> 5) * 512 + ((j >> 3) & 3) * 128 + b_l * 8 + (j & 7);

  // multimodal gate d[b][j] = img[b] . W_m[j]
  float dval = 0.0f;
  {
    const float4* ir = (const float4*)(img + (size_t)b * IMG_);
    const float4* wr = (const float4*)(W_m + (size_t)j * IMG_);
    for (int k = 0; k < IMG_ / 4; ++k) {
      const float4 a = ir[k];
      const float4 w = wr[k];
      dval += a.x * w.x + a.y * w.y + a.z * w.z + a.w * w.w;
    }
  }

  // publish h0*d = 0 into slot 0 (coalesced u32 write-through)
  if ((jj & 1) == 0)
    __hip_atomic_store((unsigned*)(ring + (size_t)q * 16384 + poff), 0u,
                       __ATOMIC_RELAXED, __HIP_MEMORY_SCOPE_AGENT);

  float cstate = 0.0f;

  __syncthreads();                      // publishes drained; bias/W ready
  if (RING == 0 && tid == 0)
    __hip_atomic_store(myslot, 1u, __ATOMIC_RELAXED, __HIP_MEMORY_SCOPE_AGENT);

  auto pollFlags = [&](unsigned target) {   // RING=0 path (R9 protocol)
    for (;;) {
      const unsigned f = __hip_atomic_load(myflags + lane, __ATOMIC_RELAXED,
                                           __HIP_MEMORY_SCOPE_AGENT);
      if (__all(f >= target)) break;
    }
  };

  short8 xr[4];
  auto xprefetch = [&](int t) {
    if (XBF) {
      const unsigned short* xb = x_bf + ((size_t)t * 4 + q) * 8192;
      #pragma unroll
      for (int sx = 0; sx < 4; ++sx)
        xr[sx] = *(const short8*)(xb + (size_t)(wv + 4 * sx) * 512 + lane * 8);
    } else {
      const float* rb = x + ((size_t)(b0 + cloc) * T_ + t) * D_ + ko8;
      #pragma unroll
      for (int sx = 0; sx < 4; ++sx) {
        const float* p = rb + (wv + 4 * sx) * 32;
        xr[sx] = pk8(*(const float4*)p, *(const float4*)(p + 4));
      }
    }
  };

  xprefetch(0);

  for (int t = 0; t < T_; ++t) {
    const unsigned short* sp = ring + (size_t)(RING ? t : (t & 1)) * SLOT_U16
                             + (size_t)q * 16384;
    short8 hfr[8];
    if (RING) {
      // ---- data-canary poll with selective re-load ----
      uint4v tmp[8];
      #pragma unroll
      for (int sh = 0; sh < 8; ++sh) {
        const unsigned short* ap = sp + (size_t)(wv + 4 * sh) * 512 + lane * 8;
        asm volatile("global_load_dwordx4 %0, %1, off sc0 sc1"
                     : "=&v"(tmp[sh]) : "v"(ap));
      }
      asm volatile("s_waitcnt vmcnt(0)" ::: "memory");
      __builtin_amdgcn_sched_barrier(0);
      unsigned pend = 0;
      #pragma unroll
      for (int sh = 0; sh < 8; ++sh) {
        bool ok = true;
        #pragma unroll
        for (int e = 0; e < 4; ++e) ok &= (tmp[sh][e] != SENT32);
        if (!__all(ok)) pend |= (1u << sh);
      }
      while (pend) {                    // re-load only stale chunks
        #pragma unroll
        for (int sh = 0; sh < 8; ++sh) {
          if (pend & (1u << sh)) {
            const unsigned short* ap = sp + (size_t)(wv + 4 * sh) * 512 + lane * 8;
            asm volatile("global_load_dwordx4 %0, %1, off sc0 sc1"
                         : "=&v"(tmp[sh]) : "v"(ap));
          }
        }
        asm volatile("s_waitcnt vmcnt(0)" ::: "memory");
        __builtin_amdgcn_sched_barrier(0);
        #pragma unroll
        for (int sh = 0; sh < 8; ++sh) {
          if (pend & (1u << sh)) {
            bool ok = true;
            #pragma unroll
            for (int e = 0; e < 4; ++e) ok &= (tmp[sh][e] != SENT32);
            if (__all(ok)) pend &= ~(1u << sh);
          }
        }
      }
      #pragma unroll
      for (int sh = 0; sh < 8; ++sh) hfr[sh] = *(short8*)&tmp[sh];
    } else {
      pollFlags((unsigned)(t + 1));
      asm volatile("" ::: "memory");
      uint4v tmp[8];
      #pragma unroll
      for (int sh = 0; sh < 8; ++sh) {
        const unsigned short* ap = sp + (size_t)(wv + 4 * sh) * 512 + lane * 8;
        asm volatile("global_load_dwordx4 %0, %1, off sc0 sc1" : "=&v"(tmp[sh]) : "v"(ap));
      }
      asm volatile("s_waitcnt vmcnt(0)" ::: "memory");
      __builtin_amdgcn_sched_barrier(0);
      #pragma unroll
      for (int sh = 0; sh < 8; ++sh)
        hfr[sh] = *(short8*)&tmp[sh];
    }

    // ---- MFMAs: 4 independent acc chains (one per gate tile) ----
    f32x4 ac[4];
    #pragma unroll
    for (int tile = 0; tile < 4; ++tile) ac[tile] = (f32x4){0.f, 0.f, 0.f, 0.f};
    #pragma unroll
    for (int sx = 0; sx < 4; ++sx) {
      #pragma unroll
      for (int tile = 0; tile < 4; ++tile)
        ac[tile] = __builtin_amdgcn_mfma_f32_16x16x32_bf16(xr[sx], wx[tile][sx], ac[tile], 0, 0, 0);
    }
    #pragma unroll
    for (int sh = 0; sh < 8; ++sh) {
      #pragma unroll
      for (int tile = 0; tile < 4; ++tile)
        ac[tile] = __builtin_amdgcn_mfma_f32_16x16x32_bf16(hfr[sh], wh[tile][sh], ac[tile], 0, 0, 0);
    }

    // ---- cross-wave reduce into buffer (t&1); C/D: col=lane&15, row=(lane>>4)*4+rr ----
    {
      const int crow = (lane >> 4) * 4;
      #pragma unroll
      for (int tile = 0; tile < 4; ++tile) {
        #pragma unroll
        for (int rr = 0; rr < 4; ++rr)
          gaccs[t & 1][wv][crow + rr][tile * 16 + cloc] = ac[tile][rr];
      }
    }
    asm volatile("s_waitcnt lgkmcnt(0)" ::: "memory");
    __builtin_amdgcn_s_barrier();
    __builtin_amdgcn_sched_barrier(0);

    // ---- cell update: thread owns (b, j) ----
    float gv[4];
    #pragma unroll
    for (int g = 0; g < 4; ++g) {
      const int c = g * 16 + jj;
      gv[g] = gaccs[t & 1][0][b_l][c] + gaccs[t & 1][1][b_l][c]
            + gaccs[t & 1][2][b_l][c] + gaccs[t & 1][3][b_l][c]
            + bias_lds[c];
    }
    const float ig = sigf(gv[0]);
    const float fg = sigf(gv[1]);
    const float gg = tanhfast(gv[2]);
    const float og = sigf(gv[3]);
    cstate = fg * cstate + ig * gg;
    const float h = og * tanhfast(cstate);

    // ---- publish h*d to slot t+1 (1 coalesced u32 per even thread) ----
    {
      const unsigned hd  = f2bf(h * dval);
      const unsigned nxt = __shfl_down((int)hd, 1);
      if ((jj & 1) == 0)
        __hip_atomic_store((unsigned*)(ring + (size_t)(RING ? (t + 1) : ((t + 1) & 1)) * SLOT_U16
                                       + (size_t)q * 16384 + poff),
                           hd | (nxt << 16),
                           __ATOMIC_RELAXED, __HIP_MEMORY_SCOPE_AGENT);
    }

    if (RING == 0) {
      __syncthreads();                  // vmcnt(0)+barrier: publishes drained
      if (t < T_ - 1 && tid == 0)
        __hip_atomic_store(myslot, (unsigned)(t + 2), __ATOMIC_RELAXED, __HIP_MEMORY_SCOPE_AGENT);
    }
    // RING=1: no epilogue barrier -- gaccs double-buffered, canary handles sync

    // off the release path:
    __builtin_nontemporal_store(h, &out[((size_t)b * T_ + t) * H_ + j]);
    if (t == T_ - 1) {
      hn[(size_t)b * H_ + j] = h;
      cn[(size_t)b * H_ + j] = cstate;
    } else {
      xprefetch(t + 1);                 // overlaps next poll
    }
  }
}

extern "C" void kernel_launch(void* const* d_in, const int* in_sizes, int n_in,
                              void* d_out, int out_size, void* d_ws, size_t ws_size,
                              hipStream_t stream) {
  (void)in_sizes; (void)n_in; (void)out_size;
  const float* x    = (const float*)d_in[0];
  const float* img  = (const float*)d_in[1];
  const float* W_ih = (const float*)d_in[2];
  const float* W_hh = (const float*)d_in[3];
  const float* b_ih = (const float*)d_in[4];
  const float* b_hh = (const float*)d_in[5];
  const float* W_m  = (const float*)d_in[6];

  float* out = (float*)d_out;
  float* hn  = out + (size_t)B_ * T_ * H_;
  float* cn  = hn + (size_t)B_ * H_;

  unsigned*       flags = (unsigned*)d_ws;
  unsigned short* ring  = (unsigned short*)((char*)d_ws + 4096);
  unsigned short* x_bf  = (unsigned short*)((char*)d_ws + 4096 + RING_BYTES);

  hipMemsetAsync(d_ws, 0, 4096, stream);   // flag array (fallback paths)

  if (ws_size >= 4096 + RING_BYTES + XBF_BYTES) {
    hipMemsetAsync(ring, 0x7F, RING_BYTES, stream);   // canary sentinel fill
    hipLaunchKernelGGL(x_repack_kernel, dim3((B_ * T_ * D_ / 8) / NTHR), dim3(NTHR), 0, stream,
                       x, x_bf);
    hipLaunchKernelGGL((mmlstm_persistent<1, 1>), dim3(NWG), dim3(NTHR), 0, stream,
                       x, x_bf, img, W_ih, W_hh, b_ih, b_hh, W_m, out, hn, cn, flags, ring);
  } else if (ws_size >= 4096 + RING_BYTES) {
    hipMemsetAsync(ring, 0x7F, RING_BYTES, stream);
    hipLaunchKernelGGL((mmlstm_persistent<1, 0>), dim3(NWG), dim3(NTHR), 0, stream,
                       x, x_bf, img, W_ih, W_hh, b_ih, b_hh, W_m, out, hn, cn, flags, ring);
  } else {
    hipLaunchKernelGGL((mmlstm_persistent<0, 0>), dim3(NWG), dim3(NTHR), 0, stream,
                       x, x_bf, img, W_ih, W_hh, b_ih, b_hh, W_m, out, hn, cn, flags, ring);
  }
}